// Round 12
// baseline (312.269 us; speedup 1.0000x reference)
//
#include <hip/hip_runtime.h>
#include <hip/hip_bf16.h>
#include <stdint.h>

typedef __bf16 bf16_t;
typedef __bf16 bf16x8 __attribute__((ext_vector_type(8)));
typedef short short8 __attribute__((ext_vector_type(8)));
typedef float f32x4 __attribute__((ext_vector_type(4)));

#define RS512  0.044194173824159216f   // 1/sqrt(512)
#define RS4608 0.014731391274719739f   // 1/sqrt(512*9)

// ---------------- K1: style vector  s[b][c] = (w[b,:] . lw[c,:])/sqrt(512) + lb[c]
__global__ void k_style(const float* __restrict__ w, const float* __restrict__ lw,
                        const float* __restrict__ lb, float* __restrict__ s) {
  int b = blockIdx.y;
  int c = blockIdx.x * 256 + threadIdx.x;
  const float4* wr = (const float4*)(w + b * 512);
  const float4* lr = (const float4*)(lw + (size_t)c * 512);
  float acc = 0.f;
#pragma unroll 4
  for (int d = 0; d < 128; ++d) {
    float4 a = wr[d], q = lr[d];
    acc += a.x * q.x + a.y * q.y + a.z * q.z + a.w * q.w;
  }
  s[b * 512 + c] = acc * RS512 + lb[c];
}

// ---------------- K2: wsq + bf16 W fragments (layout unchanged); zero-fills zbuf
__global__ void k_wprep(const float* __restrict__ cw, float* __restrict__ wsq,
                        bf16_t* __restrict__ bwf, f32x4* __restrict__ zb) {
  if (blockIdx.x == 0) zb[threadIdx.x] = (f32x4)0.f;  // 256*16B = 4KB zeros
  int idx = blockIdx.x * 256 + threadIdx.x;  // o*512 + i
  int o = idx >> 9, i = idx & 511;
  float v[9];
  float ss = 0.f;
#pragma unroll
  for (int t = 0; t < 9; ++t) {
    float x = cw[(size_t)idx * 9 + t] * RS4608;
    v[t] = x;
    ss += x * x;
  }
  wsq[idx] = ss;
  int lane = (o & 15) | (((i >> 3) & 3) << 4);
  int base_blk = (i >> 5) * 32 + (o >> 4);  // c32*32 + fo
#pragma unroll
  for (int t = 0; t < 9; ++t) {
    size_t e = ((size_t)(t * 512 + base_blk) << 9) + lane * 8 + (i & 7);
    bwf[e] = (bf16_t)v[t];
  }
}

// ---------------- K3: sigma_inv[b][o] = rsqrt( sum_i s[b,i]^2 * wsq[o,i] + eps )
__global__ void k_sigma(const float* __restrict__ s, const float* __restrict__ wsq,
                        float* __restrict__ sinv) {
  __shared__ float s2[512];
  int b = blockIdx.y;
  int o = blockIdx.x * 256 + threadIdx.x;
  for (int i = threadIdx.x; i < 512; i += 256) {
    float v = s[b * 512 + i];
    s2[i] = v * v;
  }
  __syncthreads();
  const float4* qr = (const float4*)(wsq + (size_t)o * 512);
  float acc = 0.f;
#pragma unroll 4
  for (int d = 0; d < 128; ++d) {
    float4 q = qr[d];
    acc += q.x * s2[4 * d] + q.y * s2[4 * d + 1] + q.z * s2[4 * d + 2] + q.w * s2[4 * d + 3];
  }
  sinv[b * 512 + o] = rsqrtf(acc + 1e-8f);
}

// ---------------- K4: xt in B-fragment-friendly layout:
// xt[b][h][chunk cc=0..15][kgr=0..3][col w=0..63][8 ch] = bf16( x * s )
__global__ void k_xt(const float* __restrict__ x, const float* __restrict__ s,
                     bf16_t* __restrict__ xt) {
  int ic = blockIdx.x, h = blockIdx.y, b = blockIdx.z;
  __shared__ __align__(16) bf16_t tile[8192];
  int t = threadIdx.x;
  int wcol = t & 63;
  int g = t >> 6;
#pragma unroll
  for (int blk = 0; blk < 4; ++blk) {
    int grp = blk * 4 + g;
    bf16x8 vec;
#pragma unroll
    for (int k = 0; k < 8; ++k) {
      int i = ic * 128 + grp * 8 + k;
      float v = x[(((size_t)b * 512 + i) * 64 + h) * 64 + wcol] * s[b * 512 + i];
      vec[k] = (bf16_t)v;
    }
    int chunk = grp ^ (wcol & 15);
    *(bf16x8*)((char*)tile + wcol * 256 + chunk * 16) = vec;
  }
  __syncthreads();
#pragma unroll
  for (int j = 0; j < 4; ++j) {
    int flat = j * 256 + t;
    int wo = flat >> 4, ig8 = flat & 15;
    int chunk = ig8 ^ (wo & 15);
    bf16x8 v = *(bf16x8*)((char*)tile + wo * 256 + chunk * 16);
    int cc = ic * 4 + (ig8 >> 2);   // 32-ch chunk index 0..15
    int kgr = ig8 & 3;              // 8-ch subgroup
    size_t dst = ((((size_t)b * 64 + h) * 16 + cc) << 11) + (kgr << 9) + (size_t)wo * 8;
    *(bf16x8*)(xt + dst) = v;
  }
}

// ---------------- K5: implicit-GEMM conv; W direct-to-VGPR; X in LDS (linear, conflict-free);
//                  one barrier per chunk; compiler-managed waitcnts.
#define AS1 __attribute__((address_space(1)))
#define AS3 __attribute__((address_space(3)))

__device__ __forceinline__ void gl16(const void* g, void* l) {
  __builtin_amdgcn_global_load_lds((const AS1 void*)g, (AS3 void*)l, 16, 0, 0);
}

// ws layout: zbuf@0 (4KB zeros), xt@4096 (64MB), bwf@67112960, ...
#define XT0 4096u

// LDS: [pad 1024][2 bufs][6 rows][4 kgr][64 col][16B]  rows = gr h0-1 .. h0+4
__global__ __launch_bounds__(512, 4) void k_conv(
    const char* __restrict__ wsb,      // = d_ws base (zbuf at 0, xt at XT0)
    const bf16_t* __restrict__ bwf,
    const float* __restrict__ sinv, const float* __restrict__ noise,
    const float* __restrict__ snz, const float* __restrict__ bias,
    float* __restrict__ out) {
  __shared__ __align__(16) char lds[50176];

  const int t = threadIdx.x;
  const int rq = blockIdx.x;        // output rows h0..h0+3
  const int OY = blockIdx.y;        // o0 = OY*128
  const int b = blockIdx.z;
  const int h0 = rq * 4;
  const int lane = t & 63;
  const int wv = t >> 6;            // 8 waves
  const int wm = wv & 1;            // o-offset wm*64
  const int wn = wv >> 1;           // output row h0+wn

  f32x4 acc[4][4] = {};
  bf16x8 wA[4], wB[4];

  // ---- X staging: 24 slots of 1KB per buffer; wave wv owns slots wv*3..+2.
  // All per-slot values wave-uniform -> readfirstlane to SGPR.
  uint32_t xsoff[3], xdst[3], xsel[3];
#pragma unroll
  for (int k = 0; k < 3; ++k) {
    int slot = wv * 3 + k, row = slot >> 2, q = slot & 3;
    int gr = h0 - 1 + row;
    int valid = ((unsigned)gr < 64u) ? 1 : 0;
    uint32_t so = valid ? (XT0 + (uint32_t)b * 4194304u + (uint32_t)gr * 65536u +
                           (uint32_t)q * 1024u)
                        : 0u;  // zbuf
    xsoff[k] = __builtin_amdgcn_readfirstlane(so);
    xdst[k] = __builtin_amdgcn_readfirstlane((uint32_t)(1024 + row * 4096 + q * 1024));
    xsel[k] = __builtin_amdgcn_readfirstlane((uint32_t)valid);
  }

  auto stX = [&](int k, uint32_t cxoff, int xb) {
    uint32_t co = xsel[k] ? cxoff : 0u;  // halo slots always read zbuf
    gl16(wsb + xsoff[k] + co + (size_t)(lane * 16), lds + xdst[k] + (uint32_t)(xb * 24576));
  };

  // ---- W: direct global->VGPR, fragment layout. uoff uniform per (tap, chunk).
  const size_t wbase0 = ((size_t)(OY * 8 + wm * 4)) << 10;
  auto loadW = [&](int tap, int c, bf16x8* d) {
    const char* p = (const char*)bwf + wbase0 + (((size_t)(tap * 16 + c)) << 15);
#pragma unroll
    for (int mi = 0; mi < 4; ++mi)
      d[mi] = *(const bf16x8*)(p + mi * 1024 + (size_t)(lane * 16));
  };

  // ---- B-operand LDS address: single VGPR + immediates
  const uint32_t pXbase =
      (uint32_t)(1024 + wn * 4096 + (lane >> 4) * 1024 + (lane & 15) * 16);
  const bool c0 = (lane & 15) == 0;
  const bool c15 = (lane & 15) == 15;

// one tap: 4 B ds_reads (rolling) + 16 MFMA, col-outer; AF = wA or wB (compile-time)
#define CTAP(J, XB, AF)                                                        \
  {                                                                            \
    const int ky = (J) / 3, kx = (J) % 3;                                      \
    __builtin_amdgcn_s_setprio(1);                                             \
    _Pragma("unroll") for (int col = 0; col < 4; ++col) {                      \
      short8 xv = *(const short8*)(lds + pXbase +                              \
                                   (uint32_t)((XB) * 24576 + ky * 4096 +       \
                                              col * 256 + (kx - 1) * 16));     \
      if (kx == 0 && col == 0) xv = c0 ? (short8)0 : xv;                       \
      if (kx == 2 && col == 3) xv = c15 ? (short8)0 : xv;                      \
      bf16x8 bv = __builtin_bit_cast(bf16x8, xv);                              \
      _Pragma("unroll") for (int mi = 0; mi < 4; ++mi)                         \
          acc[mi][col] = __builtin_amdgcn_mfma_f32_16x16x32_bf16(              \
              AF[mi], bv, acc[mi][col], 0, 0, 0);                              \
    }                                                                          \
    __builtin_amdgcn_s_setprio(0);                                             \
  }

// one chunk: 9 taps, no internal barriers; X[c+1] staged at taps 0-2; W prefetched
// 1 tap ahead into the other reg-buffer; one __syncthreads at the end.
#define CHUNK(C, XB, P, LAST)                                                  \
  {                                                                            \
    _Pragma("unroll") for (int j = 0; j < 9; ++j) {                            \
      if (!(LAST) && j < 3) stX(j, (uint32_t)(((C) + 1) * 4096), (XB) ^ 1);    \
      if (j < 8) {                                                             \
        if (((j + (P)) & 1) == 0) loadW(j + 1, (C), wB);                       \
        else loadW(j + 1, (C), wA);                                            \
      } else if (!(LAST)) {                                                    \
        if (((j + (P)) & 1) == 0) loadW(0, (C) + 1, wB);                       \
        else loadW(0, (C) + 1, wA);                                            \
      }                                                                        \
      if (((j + (P)) & 1) == 0) CTAP(j, (XB), wA)                              \
      else CTAP(j, (XB), wB)                                                   \
    }                                                                          \
    __syncthreads();                                                           \
  }

  // prologue: stage X[0] (halo rows come from zbuf), preload W(tap0,chunk0)
#pragma unroll
  for (int k = 0; k < 3; ++k) stX(k, 0u, 0);
  loadW(0, 0, wA);
  __syncthreads();

#pragma unroll 1
  for (int ci = 0; ci < 7; ++ci) {
    const int c = ci * 2;
    CHUNK(c, 0, 0, 0);
    CHUNK(c + 1, 1, 1, 0);
  }
  CHUNK(14, 0, 0, 0);
  CHUNK(15, 1, 1, 1);

  // epilogue: demod scale + noise + bias + leaky relu (one output row per wave)
  const float* sb = sinv + b * 512;
  const int og = OY * 128 + wm * 64 + ((lane >> 4) << 2);
  const int colb = lane & 15;
  const int prow = h0 + wn;
  float nzv[4];
#pragma unroll
  for (int col = 0; col < 4; ++col)
    nzv[col] = noise[(size_t)b * 4096 + prow * 64 + col * 16 + colb];
#pragma unroll
  for (int mi = 0; mi < 4; ++mi) {
#pragma unroll
    for (int r = 0; r < 4; ++r) {
      int o = og + mi * 16 + r;
      float sv = sb[o];
      float nw = snz[o];
      float bv = bias[o];
      float* orow = out + (((size_t)b * 512 + o) * 64 + prow) * 64;
#pragma unroll
      for (int col = 0; col < 4; ++col) {
        float v = acc[mi][col][r] * sv + nw * nzv[col] + bv;
        orow[col * 16 + colb] = v > 0.f ? v : 0.2f * v;
      }
    }
  }
}

extern "C" void kernel_launch(void* const* d_in, const int* in_sizes, int n_in,
                              void* d_out, int out_size, void* d_ws, size_t ws_size,
                              hipStream_t stream) {
  const float* x     = (const float*)d_in[0];
  const float* w     = (const float*)d_in[1];
  const float* noise = (const float*)d_in[2];
  const float* lw    = (const float*)d_in[3];
  const float* lb    = (const float*)d_in[4];
  const float* cw    = (const float*)d_in[5];
  const float* snz   = (const float*)d_in[6];
  const float* bias  = (const float*)d_in[7];
  float* out = (float*)d_out;

  char* ws = (char*)d_ws;
  char*   zbuf = ws;                            //      4,096 B zeros (also xt edge pad)
  bf16_t* xt   = (bf16_t*)(ws + 4096);          // 67,108,864 B : new fragment layout
  bf16_t* bwf  = (bf16_t*)(ws + 67112960);      //  4,718,592 B : W fragments
  float*  s    = (float*)(ws + 71831552);       //     32,768 B
  float*  sinv = (float*)(ws + 71864320);       //     32,768 B
  float*  wsq  = (float*)(ws + 71897088);       //  1,048,576 B

  k_style<<<dim3(2, 16), 256, 0, stream>>>(w, lw, lb, s);
  k_wprep<<<dim3(1024), 256, 0, stream>>>(cw, wsq, bwf, (f32x4*)zbuf);
  k_sigma<<<dim3(2, 16), 256, 0, stream>>>(s, wsq, sinv);
  k_xt<<<dim3(4, 64, 16), 256, 0, stream>>>(x, s, xt);
  k_conv<<<dim3(16, 4, 16), 512, 0, stream>>>(ws, bwf, sinv, noise, snz, bias, out);
}